// Round 15
// baseline (379.298 us; speedup 1.0000x reference)
//
#include <hip/hip_runtime.h>
#include <hip/hip_bf16.h>
#include <stdint.h>

// Problem constants (B=4, S=2048, H=1024, E=8, K=2)
#define E_    8
#define H_    1024
#define NTOK  8192           // B*S
#define KSEL  2
#define NSLOT (NTOK * KSEL)  // 16384

typedef __attribute__((ext_vector_type(8))) short   short8_t;  // 8 bf16 in 4 VGPRs
typedef __attribute__((ext_vector_type(4))) float   f32x4;

// GEMM tiling: 128x128, BK=64, 4 waves. Reg-staged bf16 (global->VGPR->ds_write),
// XOR-SWIZZLED LINEAR LDS (32KB total: unit' = unit ^ (row&7); R4-verified
// 0-conflict involution — legal here because reg-staging means plain ds_write,
// no gload_lds lane-order constraint). 32KB -> 5 blocks/CU -> capacity 1280 >
// grid 1088 -> SINGLE dispatch round (R14 post-mortem: 36.9KB gave capacity
// 1024 < 1088 -> 2-round makespan, the real limiter).
#define BM 128
#define BN 128
#define BK 64
#define MAXMT 136
#define NT    (H_ / BN)      // 8 N-tiles
#define NWG   (MAXMT * NT)   // 1088, divisible by 8 (bijective XCD swizzle)

// ---- workspace layout (bytes) ----
#define CNT_OFF   0
#define CUR_OFF   64
#define TOK_OFF   1024                     // NSLOT ints
#define WSL_OFF   (TOK_OFF + NSLOT * 4)    // NSLOT floats
#define XB_OFF    (1 << 18)                              // bf16 x (16.7 MB)
#define H1_OFF    (XB_OFF + (NSLOT + 256) * H_ * 2)
#define W1T_OFF   (H1_OFF + (NSLOT + 256) * H_ * 2)
#define W2T_OFF   (W1T_OFF + E_ * H_ * H_ * 2)

// ---------------------------------------------------------------------------
__global__ void route_count(const int* __restrict__ idx, int* __restrict__ cnt) {
  int p = blockIdx.x * 256 + threadIdx.x;
  if (p < NSLOT) atomicAdd(&cnt[idx[p]], 1);
}

__global__ void route_scatter(const int* __restrict__ idx, const float* __restrict__ tkw,
                              const int* __restrict__ cnt, int* __restrict__ cur,
                              int* __restrict__ tok, float* __restrict__ wsl) {
  int p = blockIdx.x * 256 + threadIdx.x;
  if (p < NSLOT) {
    const int e = idx[p];
    int off = 0;
#pragma unroll
    for (int i = 0; i < E_; ++i) off += (i < e) ? cnt[i] : 0;
    const int pos = off + atomicAdd(&cur[e], 1);
    tok[pos] = p >> 1;
    wsl[pos] = tkw[p];
  }
}

// ---------------------------------------------------------------------------
// xb = (bf16) x   — 16 elems/thread, 2048 blocks (R14-verified)
__global__ void xcast(const float* __restrict__ x, __hip_bfloat16* __restrict__ xb) {
  const size_t base = ((size_t)blockIdx.x * 256 + threadIdx.x) * 16;
#pragma unroll
  for (int h = 0; h < 2; ++h) {
    f32x4 v0 = *(const f32x4*)(x + base + h * 8);
    f32x4 v1 = *(const f32x4*)(x + base + h * 8 + 4);
    union { __hip_bfloat16 b[8]; uint2 u[2]; } cv;
#pragma unroll
    for (int j = 0; j < 4; ++j) {
      cv.b[j]     = __float2bfloat16(v0[j]);
      cv.b[4 + j] = __float2bfloat16(v1[j]);
    }
    *(uint2*)(xb + base + h * 8)     = cv.u[0];
    *(uint2*)(xb + base + h * 8 + 4) = cv.u[1];
  }
}

// ---------------------------------------------------------------------------
// wt[e][f][h] = (bf16) w[e][h][f].  64x64 tiles, 256 threads (R13-verified).
__global__ void transpose_cast(const float* __restrict__ w1, const float* __restrict__ w2,
                               __hip_bfloat16* __restrict__ wt1, __hip_bfloat16* __restrict__ wt2) {
  __shared__ __hip_bfloat16 t[64][65];
  const int z = blockIdx.z;
  const float* W = (z < E_ ? w1 : w2) + ((size_t)(z & 7) << 20);
  __hip_bfloat16* WT = (z < E_ ? wt1 : wt2) + ((size_t)(z & 7) << 20);
  const int h0 = blockIdx.y * 64, f0 = blockIdx.x * 64;
  const int tid = threadIdx.x;
  const int tx = tid & 63, ty = tid >> 6;
#pragma unroll
  for (int i = 0; i < 16; ++i) {
    const int hl = i * 4 + ty;
    t[hl][tx] = __float2bfloat16(W[(size_t)(h0 + hl) * H_ + f0 + tx]);
  }
  __syncthreads();
  const int htx = tid & 15;
  const int fy  = tid >> 4;
#pragma unroll
  for (int j = 0; j < 4; ++j) {
    const int f = j * 16 + fy;
    union { __hip_bfloat16 h[4]; uint2 u; } v;
#pragma unroll
    for (int k = 0; k < 4; ++k) v.h[k] = t[htx * 4 + k][f];
    *reinterpret_cast<uint2*>(&WT[(size_t)(f0 + f) * H_ + h0 + htx * 4]) = v.u;
  }
}

// ---------------------------------------------------------------------------
// Grouped GEMM, single-buffer reg-staged, raw-barrier loop (R12/R13-verified):
//   { loadreg(kt+1) ; compute(kt) } -> lgkm0+bar -> dswrite(kt+1) -> lgkm0+bar
//   EPI=0: A = xb rows gathered via tok;  h1 = relu(AW^T+b)
//   EPI=1: A = h1 rows (linear);          out[tok[p]] += wsl[p]*(AW^T+b)
#define FENCE_BAR() do {                                   \
    asm volatile("s_waitcnt lgkmcnt(0)" ::: "memory");     \
    __builtin_amdgcn_s_barrier();                          \
    __builtin_amdgcn_sched_barrier(0);                     \
  } while (0)

template <int EPI>
__launch_bounds__(256, 5)
__global__ void moe_gemm(const __hip_bfloat16* __restrict__ Asrc,  // xb (EPI=0) / h1 (EPI=1)
                         const __hip_bfloat16* __restrict__ Wt,    // [E][H][H] (f-major)
                         const float* __restrict__ bias,           // [E][H]
                         __hip_bfloat16* __restrict__ h1out,
                         float* __restrict__ out,
                         const int* __restrict__ cnt,
                         const int* __restrict__ tok, const float* __restrict__ wsl) {
  // T1: bijective XCD swizzle (NWG % 8 == 0)
  const int wgid = (blockIdx.x & 7) * (NWG / 8) + (blockIdx.x >> 3);
  const int bt = wgid >> 3;
  const int nt = wgid & 7;

  // inline offs/toff prefix from cnt[8]
  int cn[E_];
#pragma unroll
  for (int i = 0; i < E_; ++i) cn[i] = cnt[i];
  int e = -1, mt = 0, count = 0, arow0 = 0;
  {
    int tacc = 0, sacc = 0;
#pragma unroll
    for (int i = 0; i < E_; ++i) {
      const int nti = (cn[i] + BM - 1) / BM;
      if (e < 0 && bt < tacc + nti) { e = i; mt = bt - tacc; count = cn[i]; arow0 = sacc + mt * BM; }
      tacc += nti; sacc += cn[i];
    }
  }
  if (e < 0) return;
  const size_t Arow0 = (size_t)arow0;

  const int tid = threadIdx.x;
  const int lane = tid & 63;
  const int wid = tid >> 6;
  const int wm = wid >> 1, wn = wid & 1;
  const int l15 = lane & 15, hi = lane >> 4, l7 = lane & 7;

  const __hip_bfloat16* Bexp = Wt + ((size_t)e << 20) + (size_t)(nt * BN) * H_;

  __shared__ __hip_bfloat16 smA[BM * BK];  // 16 KB
  __shared__ __hip_bfloat16 smB[BN * BK];  // 32 KB total -> 5 blocks/CU

  const int srow = tid >> 3;         // 0..31
  const int sun  = (tid & 7) * 8;    // linear global source offset (coalesced)
  // LDS phys unit for ds_write: logical unit (tid&7) of row r stored at (u^(r&7))
  const int swu  = (((tid & 7) ^ (srow & 7)) * 8);

  const __hip_bfloat16* aptr[4];
#pragma unroll
  for (int i = 0; i < 4; ++i) {
    if constexpr (EPI == 0) {
      int p = arow0 + i * 32 + srow;
      if (p > NSLOT - 1) p = NSLOT - 1;
      aptr[i] = Asrc + (size_t)tok[p] * H_ + sun;
    } else {
      aptr[i] = Asrc + (Arow0 + i * 32 + srow) * H_ + sun;
    }
  }
  const __hip_bfloat16* bptr = Bexp + (size_t)srow * H_ + sun;

  short8_t ra[4], rb[4];

  auto loadreg = [&](int kt) {
#pragma unroll
    for (int i = 0; i < 4; ++i) {
      ra[i] = *(const short8_t*)(aptr[i] + kt * BK);
      rb[i] = *(const short8_t*)(bptr + (size_t)(i * 32) * H_ + kt * BK);
    }
  };
  auto dswrite = [&]() {
#pragma unroll
    for (int i = 0; i < 4; ++i) {
      *(short8_t*)&smA[(i * 32 + srow) * BK + swu] = ra[i];
      *(short8_t*)&smB[(i * 32 + srow) * BK + swu] = rb[i];
    }
  };

  f32x4 acc[4][4];
#pragma unroll
  for (int mi = 0; mi < 4; ++mi)
#pragma unroll
    for (int ni = 0; ni < 4; ++ni) acc[mi][ni] = f32x4{0.f, 0.f, 0.f, 0.f};

  // ds_read: logical unit (ks*4+hi) of row r at phys (ks*4+hi)^(r&7); r&7 == l7
  const int pu[2] = { ((0 * 4 + hi) ^ l7) * 8, ((1 * 4 + hi) ^ l7) * 8 };

  auto compute = [&]() {
#pragma unroll
    for (int ks = 0; ks < 2; ++ks) {
      short8_t a[4], b[4];
#pragma unroll
      for (int mi = 0; mi < 4; ++mi)
        a[mi] = *(const short8_t*)&smA[(wm * 64 + mi * 16 + l15) * BK + pu[ks]];
#pragma unroll
      for (int ni = 0; ni < 4; ++ni)
        b[ni] = *(const short8_t*)&smB[(wn * 64 + ni * 16 + l15) * BK + pu[ks]];
#pragma unroll
      for (int mi = 0; mi < 4; ++mi)
#pragma unroll
        for (int ni = 0; ni < 4; ++ni)
          acc[mi][ni] = __builtin_amdgcn_mfma_f32_16x16x32_bf16(a[mi], b[ni], acc[mi][ni], 0, 0, 0);
    }
  };

  const int KT = H_ / BK;  // 16

  loadreg(0);
  dswrite();
  FENCE_BAR();

  for (int kt = 0; kt < KT; ++kt) {
    if (kt + 1 < KT) loadreg(kt + 1);  // in flight through compute + barrier
    compute();
    if (kt + 1 < KT) {
      FENCE_BAR();                      // all waves done reading tile kt
      dswrite();                        // counted per-reg vmcnt waits only
      FENCE_BAR();                      // writes visible
    }
  }

  // ---- epilogue: per-(mi,r) hoisted bound check (R13-verified) ----
  const int colb = nt * BN + wn * 64;
  float bv[4];
#pragma unroll
  for (int ni = 0; ni < 4; ++ni) bv[ni] = bias[e * H_ + colb + ni * 16 + l15];

  if constexpr (EPI == 0) {
#pragma unroll
    for (int mi = 0; mi < 4; ++mi)
#pragma unroll
      for (int r = 0; r < 4; ++r) {
        const int lr = wm * 64 + mi * 16 + hi * 4 + r;
        if (mt * BM + lr < count) {
          __hip_bfloat16* rp = h1out + (Arow0 + lr) * H_ + colb;
#pragma unroll
          for (int ni = 0; ni < 4; ++ni) {
            float v = acc[mi][ni][r] + bv[ni];
            rp[ni * 16 + l15] = __float2bfloat16(fmaxf(v, 0.f));
          }
        }
      }
  } else {
#pragma unroll
    for (int mi = 0; mi < 4; ++mi)
#pragma unroll
      for (int r = 0; r < 4; ++r) {
        const int lr = wm * 64 + mi * 16 + hi * 4 + r;
        if (mt * BM + lr < count) {
          const int p = arow0 + lr;
          float* rp = out + (size_t)tok[p] * H_ + colb;
          const float w = wsl[p];
#pragma unroll
          for (int ni = 0; ni < 4; ++ni)
            atomicAdd(rp + ni * 16 + l15, (acc[mi][ni][r] + bv[ni]) * w);
        }
      }
  }
}

// ---------------------------------------------------------------------------
extern "C" void kernel_launch(void* const* d_in, const int* in_sizes, int n_in,
                              void* d_out, int out_size, void* d_ws, size_t ws_size,
                              hipStream_t stream) {
  const float* x   = (const float*)d_in[0];
  const int*   idx = (const int*)d_in[1];
  const float* tkw = (const float*)d_in[2];
  const float* w1  = (const float*)d_in[3];
  const float* b1  = (const float*)d_in[4];
  const float* w2  = (const float*)d_in[5];
  const float* b2  = (const float*)d_in[6];
  float* out = (float*)d_out;

  uint8_t* ws = (uint8_t*)d_ws;
  int*   cnt  = (int*)(ws + CNT_OFF);
  int*   cur  = (int*)(ws + CUR_OFF);
  int*   tok  = (int*)(ws + TOK_OFF);
  float* wsl  = (float*)(ws + WSL_OFF);
  __hip_bfloat16* xb  = (__hip_bfloat16*)(ws + XB_OFF);
  __hip_bfloat16* h1  = (__hip_bfloat16*)(ws + H1_OFF);
  __hip_bfloat16* w1t = (__hip_bfloat16*)(ws + W1T_OFF);
  __hip_bfloat16* w2t = (__hip_bfloat16*)(ws + W2T_OFF);

  hipMemsetAsync(ws, 0, 1024, stream);
  hipMemsetAsync(d_out, 0, (size_t)out_size * sizeof(float), stream);

  xcast<<<NTOK * H_ / (256 * 16), 256, 0, stream>>>(x, xb);
  transpose_cast<<<dim3(H_ / 64, H_ / 64, 2 * E_), 256, 0, stream>>>(w1, w2, w1t, w2t);

  route_count<<<NSLOT / 256, 256, 0, stream>>>(idx, cnt);
  route_scatter<<<NSLOT / 256, 256, 0, stream>>>(idx, tkw, cnt, cur, tok, wsl);

  moe_gemm<0><<<NWG, 256, 0, stream>>>(xb, w1t, b1, h1, nullptr, cnt, tok, wsl);
  moe_gemm<1><<<NWG, 256, 0, stream>>>(h1, w2t, b2, nullptr, out, cnt, tok, wsl);
}

// Round 16
// 298.889 us; speedup vs baseline: 1.2690x; 1.2690x over previous
//
#include <hip/hip_runtime.h>
#include <hip/hip_bf16.h>
#include <stdint.h>

// Problem constants (B=4, S=2048, H=1024, E=8, K=2)
#define E_    8
#define H_    1024
#define NTOK  8192           // B*S
#define KSEL  2
#define NSLOT (NTOK * KSEL)  // 16384

typedef __attribute__((ext_vector_type(8))) short   short8_t;  // 8 bf16 in 4 VGPRs
typedef __attribute__((ext_vector_type(4))) float   f32x4;

// GEMM tiling: 128x128, BK=64, 4 waves. Reg-staged (global->VGPR->ds_write),
// PADDED LDS (stride 72 -> benign <=2-way conflicts; R15 A/B: padded beats
// XOR-swizzle at this occupancy), single buffer, raw barriers (lgkmcnt-only):
// loads for kt+1 stay in flight across the barrier. lb(256,4) -> 4 blocks/CU
// (R15: forcing 5/CU thrashes L2, FETCH +30%, dur +34%).
#define BM 128
#define BN 128
#define BK 64
#define LDP 72               // padded row stride (elems)
#define MAXMT 136
#define NT    (H_ / BN)      // 8 N-tiles
#define NWG   (MAXMT * NT)   // 1088, divisible by 8 (bijective XCD swizzle)

// ---- workspace layout (bytes) ----
#define CNT_OFF   0
#define CUR_OFF   64
#define TOK_OFF   1024                     // NSLOT ints
#define WSL_OFF   (TOK_OFF + NSLOT * 4)    // NSLOT floats
#define H1_OFF    (1 << 18)
#define W1T_OFF   (H1_OFF + (NSLOT + 256) * H_ * 2)
#define W2T_OFF   (W1T_OFF + E_ * H_ * H_ * 2)

// ---------------------------------------------------------------------------
__global__ void route_count(const int* __restrict__ idx, int* __restrict__ cnt) {
  int p = blockIdx.x * 256 + threadIdx.x;
  if (p < NSLOT) atomicAdd(&cnt[idx[p]], 1);
}

// scatter with inline prefix from final counts (R14-verified)
__global__ void route_scatter(const int* __restrict__ idx, const float* __restrict__ tkw,
                              const int* __restrict__ cnt, int* __restrict__ cur,
                              int* __restrict__ tok, float* __restrict__ wsl) {
  int p = blockIdx.x * 256 + threadIdx.x;
  if (p < NSLOT) {
    const int e = idx[p];
    int off = 0;
#pragma unroll
    for (int i = 0; i < E_; ++i) off += (i < e) ? cnt[i] : 0;
    const int pos = off + atomicAdd(&cur[e], 1);
    tok[pos] = p >> 1;
    wsl[pos] = tkw[p];
  }
}

// ---------------------------------------------------------------------------
// wt[e][f][h] = (bf16) w[e][h][f].  64x64 tiles, 256 threads (R13-verified).
__global__ void transpose_cast(const float* __restrict__ w1, const float* __restrict__ w2,
                               __hip_bfloat16* __restrict__ wt1, __hip_bfloat16* __restrict__ wt2) {
  __shared__ __hip_bfloat16 t[64][65];
  const int z = blockIdx.z;
  const float* W = (z < E_ ? w1 : w2) + ((size_t)(z & 7) << 20);
  __hip_bfloat16* WT = (z < E_ ? wt1 : wt2) + ((size_t)(z & 7) << 20);
  const int h0 = blockIdx.y * 64, f0 = blockIdx.x * 64;
  const int tid = threadIdx.x;
  const int tx = tid & 63, ty = tid >> 6;
#pragma unroll
  for (int i = 0; i < 16; ++i) {
    const int hl = i * 4 + ty;
    t[hl][tx] = __float2bfloat16(W[(size_t)(h0 + hl) * H_ + f0 + tx]);
  }
  __syncthreads();
  const int htx = tid & 15;
  const int fy  = tid >> 4;
#pragma unroll
  for (int j = 0; j < 4; ++j) {
    const int f = j * 16 + fy;
    union { __hip_bfloat16 h[4]; uint2 u; } v;
#pragma unroll
    for (int k = 0; k < 4; ++k) v.h[k] = t[htx * 4 + k][f];
    *reinterpret_cast<uint2*>(&WT[(size_t)(f0 + f) * H_ + h0 + htx * 4]) = v.u;
  }
}

// ---------------------------------------------------------------------------
// Grouped GEMM, single-buffer reg-staged, raw-barrier loop (R12-R14 verified):
//   { loadreg(kt+1) ; compute(kt) } -> lgkm0+bar -> dswrite(kt+1) -> lgkm0+bar
//   EPI=0: A = gathered f32 x-rows via tok (cvt at ds_write); h1 = relu(AW^T+b)
//   EPI=1: A = h1 rows (linear bf16);  out[tok[p]] += wsl[p]*(AW^T+b)
#define FENCE_BAR() do {                                   \
    asm volatile("s_waitcnt lgkmcnt(0)" ::: "memory");     \
    __builtin_amdgcn_s_barrier();                          \
    __builtin_amdgcn_sched_barrier(0);                     \
  } while (0)

template <int EPI>
__launch_bounds__(256, 4)
__global__ void moe_gemm(const float* __restrict__ Xf,            // EPI=0 A source
                         const __hip_bfloat16* __restrict__ Ah,   // EPI=1 A source
                         const __hip_bfloat16* __restrict__ Wt,   // [E][H][H] (f-major)
                         const float* __restrict__ bias,          // [E][H]
                         __hip_bfloat16* __restrict__ h1out,
                         float* __restrict__ out,
                         const int* __restrict__ cnt,
                         const int* __restrict__ tok, const float* __restrict__ wsl) {
  // T1: bijective XCD swizzle (NWG % 8 == 0)
  const int wgid = (blockIdx.x & 7) * (NWG / 8) + (blockIdx.x >> 3);
  const int bt = wgid >> 3;
  const int nt = wgid & 7;

  // inline offs/toff prefix from cnt[8] (R14-verified)
  int cn[E_];
#pragma unroll
  for (int i = 0; i < E_; ++i) cn[i] = cnt[i];
  int e = -1, mt = 0, count = 0, arow0 = 0;
  {
    int tacc = 0, sacc = 0;
#pragma unroll
    for (int i = 0; i < E_; ++i) {
      const int nti = (cn[i] + BM - 1) / BM;
      if (e < 0 && bt < tacc + nti) { e = i; mt = bt - tacc; count = cn[i]; arow0 = sacc + mt * BM; }
      tacc += nti; sacc += cn[i];
    }
  }
  if (e < 0) return;
  const size_t Arow0 = (size_t)arow0;

  const int tid = threadIdx.x;
  const int lane = tid & 63;
  const int wid = tid >> 6;
  const int wm = wid >> 1, wn = wid & 1;
  const int l15 = lane & 15, hi = lane >> 4;

  const __hip_bfloat16* Bexp = Wt + ((size_t)e << 20) + (size_t)(nt * BN) * H_;

  __shared__ __hip_bfloat16 smA[BM * LDP];  // 18.4 KB
  __shared__ __hip_bfloat16 smB[BN * LDP];  // 36.9 KB total -> 4 blocks/CU

  const int srow = tid >> 3;         // 0..31
  const int sun  = (tid & 7) * 8;

  const float*          aptrF[4];
  const __hip_bfloat16* aptrH[4];
#pragma unroll
  for (int i = 0; i < 4; ++i) {
    if constexpr (EPI == 0) {
      int p = arow0 + i * 32 + srow;
      if (p > NSLOT - 1) p = NSLOT - 1;
      aptrF[i] = Xf + (size_t)tok[p] * H_ + sun;
    } else {
      aptrH[i] = Ah + (Arow0 + i * 32 + srow) * H_ + sun;
    }
  }
  const __hip_bfloat16* bptr = Bexp + (size_t)srow * H_ + sun;

  f32x4    fa[4][2];
  short8_t ra[4];
  short8_t rb[4];

  auto loadreg = [&](int kt) {
#pragma unroll
    for (int i = 0; i < 4; ++i) {
      if constexpr (EPI == 0) {
        const f32x4* ap = (const f32x4*)(aptrF[i] + kt * BK);
        fa[i][0] = ap[0];
        fa[i][1] = ap[1];
      } else {
        ra[i] = *(const short8_t*)(aptrH[i] + kt * BK);
      }
      rb[i] = *(const short8_t*)(bptr + (size_t)(i * 32) * H_ + kt * BK);
    }
  };
  auto dswrite = [&]() {
#pragma unroll
    for (int i = 0; i < 4; ++i) {
      short8_t av;
      if constexpr (EPI == 0) {
        union { __hip_bfloat16 h[8]; short8_t v; } cv;
#pragma unroll
        for (int j = 0; j < 4; ++j) {
          cv.h[j]     = __float2bfloat16(fa[i][0][j]);
          cv.h[4 + j] = __float2bfloat16(fa[i][1][j]);
        }
        av = cv.v;
      } else {
        av = ra[i];
      }
      *(short8_t*)&smA[(i * 32 + srow) * LDP + sun] = av;
      *(short8_t*)&smB[(i * 32 + srow) * LDP + sun] = rb[i];
    }
  };

  f32x4 acc[4][4];
#pragma unroll
  for (int mi = 0; mi < 4; ++mi)
#pragma unroll
    for (int ni = 0; ni < 4; ++ni) acc[mi][ni] = f32x4{0.f, 0.f, 0.f, 0.f};

  auto compute = [&]() {
#pragma unroll
    for (int ks = 0; ks < 2; ++ks) {
      short8_t a[4], b[4];
#pragma unroll
      for (int mi = 0; mi < 4; ++mi)
        a[mi] = *(const short8_t*)&smA[(wm * 64 + mi * 16 + l15) * LDP + (ks * 4 + hi) * 8];
#pragma unroll
      for (int ni = 0; ni < 4; ++ni)
        b[ni] = *(const short8_t*)&smB[(wn * 64 + ni * 16 + l15) * LDP + (ks * 4 + hi) * 8];
#pragma unroll
      for (int mi = 0; mi < 4; ++mi)
#pragma unroll
        for (int ni = 0; ni < 4; ++ni)
          acc[mi][ni] = __builtin_amdgcn_mfma_f32_16x16x32_bf16(a[mi], b[ni], acc[mi][ni], 0, 0, 0);
    }
  };

  const int KT = H_ / BK;  // 16

  loadreg(0);
  dswrite();
  FENCE_BAR();

  for (int kt = 0; kt < KT; ++kt) {
    if (kt + 1 < KT) loadreg(kt + 1);  // in flight through compute + barrier
    compute();
    if (kt + 1 < KT) {
      FENCE_BAR();                      // all waves done reading tile kt
      dswrite();                        // counted per-reg vmcnt waits only
      FENCE_BAR();                      // writes visible
    }
  }

  // ---- epilogue: per-(mi,r) hoisted bound check (R13-verified) ----
  const int colb = nt * BN + wn * 64;
  float bv[4];
#pragma unroll
  for (int ni = 0; ni < 4; ++ni) bv[ni] = bias[e * H_ + colb + ni * 16 + l15];

  if constexpr (EPI == 0) {
#pragma unroll
    for (int mi = 0; mi < 4; ++mi)
#pragma unroll
      for (int r = 0; r < 4; ++r) {
        const int lr = wm * 64 + mi * 16 + hi * 4 + r;
        if (mt * BM + lr < count) {
          __hip_bfloat16* rp = h1out + (Arow0 + lr) * H_ + colb;
#pragma unroll
          for (int ni = 0; ni < 4; ++ni) {
            float v = acc[mi][ni][r] + bv[ni];
            rp[ni * 16 + l15] = __float2bfloat16(fmaxf(v, 0.f));
          }
        }
      }
  } else {
#pragma unroll
    for (int mi = 0; mi < 4; ++mi)
#pragma unroll
      for (int r = 0; r < 4; ++r) {
        const int lr = wm * 64 + mi * 16 + hi * 4 + r;
        if (mt * BM + lr < count) {
          const int p = arow0 + lr;
          float* rp = out + (size_t)tok[p] * H_ + colb;
          const float w = wsl[p];
#pragma unroll
          for (int ni = 0; ni < 4; ++ni)
            atomicAdd(rp + ni * 16 + l15, (acc[mi][ni][r] + bv[ni]) * w);
        }
      }
  }
}

// ---------------------------------------------------------------------------
extern "C" void kernel_launch(void* const* d_in, const int* in_sizes, int n_in,
                              void* d_out, int out_size, void* d_ws, size_t ws_size,
                              hipStream_t stream) {
  const float* x   = (const float*)d_in[0];
  const int*   idx = (const int*)d_in[1];
  const float* tkw = (const float*)d_in[2];
  const float* w1  = (const float*)d_in[3];
  const float* b1  = (const float*)d_in[4];
  const float* w2  = (const float*)d_in[5];
  const float* b2  = (const float*)d_in[6];
  float* out = (float*)d_out;

  uint8_t* ws = (uint8_t*)d_ws;
  int*   cnt  = (int*)(ws + CNT_OFF);
  int*   cur  = (int*)(ws + CUR_OFF);
  int*   tok  = (int*)(ws + TOK_OFF);
  float* wsl  = (float*)(ws + WSL_OFF);
  __hip_bfloat16* h1  = (__hip_bfloat16*)(ws + H1_OFF);
  __hip_bfloat16* w1t = (__hip_bfloat16*)(ws + W1T_OFF);
  __hip_bfloat16* w2t = (__hip_bfloat16*)(ws + W2T_OFF);

  hipMemsetAsync(ws, 0, 1024, stream);
  hipMemsetAsync(d_out, 0, (size_t)out_size * sizeof(float), stream);

  transpose_cast<<<dim3(H_ / 64, H_ / 64, 2 * E_), 256, 0, stream>>>(w1, w2, w1t, w2t);

  route_count<<<NSLOT / 256, 256, 0, stream>>>(idx, cnt);
  route_scatter<<<NSLOT / 256, 256, 0, stream>>>(idx, tkw, cnt, cur, tok, wsl);

  moe_gemm<0><<<NWG, 256, 0, stream>>>(x, nullptr, w1t, b1, h1, nullptr, cnt, tok, wsl);
  moe_gemm<1><<<NWG, 256, 0, stream>>>(nullptr, h1, w2t, b2, nullptr, out, cnt, tok, wsl);
}

// Round 17
// 296.216 us; speedup vs baseline: 1.2805x; 1.0090x over previous
//
#include <hip/hip_runtime.h>
#include <hip/hip_bf16.h>
#include <stdint.h>

// Problem constants (B=4, S=2048, H=1024, E=8, K=2)
#define E_    8
#define H_    1024
#define NTOK  8192           // B*S
#define KSEL  2
#define NSLOT (NTOK * KSEL)  // 16384

typedef __attribute__((ext_vector_type(8))) short   short8_t;  // 8 bf16 in 4 VGPRs
typedef __attribute__((ext_vector_type(4))) float   f32x4;

// GEMM tiling: 160x128, BK=64, 4 waves (2Mx2N, per-wave 80x64, acc[5][4]).
// Reg-staged bf16 (global->VGPR->ds_write), XOR-swizzled LDS (LDP=64 ->
// 36.9KB total -> 4 blocks/CU), raw barriers (lgkmcnt-only). WHY BM=160:
// tiles ~= 8*13*8 ~= 832, NWG=880 <= capacity 1024 -> ALL blocks resident at
// t=0 -> single dispatch round (R14/R16 analysis: BM=128's grid ~1045 > 1024
// forced a 2-round makespan = the dominant GEMM cost; R15: >4 blocks/CU
// thrashes L2, so capacity can't grow — tiles must shrink in count).
#define BM 160
#define BN 128
#define BK 64
#define MAXMT 110            // ceil(16384/160)=103 + 7 slack
#define NT    (H_ / BN)      // 8 N-tiles
#define NWG   (MAXMT * NT)   // 880, div by 8 (bijective XCD swizzle), <= 1024

// ---- workspace layout (bytes) ----
#define CNT_OFF   0
#define CUR_OFF   64
#define TOK_OFF   1024                     // NSLOT ints
#define WSL_OFF   (TOK_OFF + NSLOT * 4)    // NSLOT floats
#define XB_OFF    (1 << 18)                              // bf16 x (16.8 MB)
#define H1_OFF    (XB_OFF + (size_t)NTOK * H_ * 2)
#define W1T_OFF   (H1_OFF + (size_t)(NSLOT + 2048) * H_ * 2)  // +2048 rows: tile-slack reads
#define W2T_OFF   (W1T_OFF + (size_t)E_ * H_ * H_ * 2)

// ---------------------------------------------------------------------------
__global__ void route_count(const int* __restrict__ idx, int* __restrict__ cnt) {
  int p = blockIdx.x * 256 + threadIdx.x;
  if (p < NSLOT) atomicAdd(&cnt[idx[p]], 1);
}

__global__ void route_scatter(const int* __restrict__ idx, const float* __restrict__ tkw,
                              const int* __restrict__ cnt, int* __restrict__ cur,
                              int* __restrict__ tok, float* __restrict__ wsl) {
  int p = blockIdx.x * 256 + threadIdx.x;
  if (p < NSLOT) {
    const int e = idx[p];
    int off = 0;
#pragma unroll
    for (int i = 0; i < E_; ++i) off += (i < e) ? cnt[i] : 0;
    const int pos = off + atomicAdd(&cur[e], 1);
    tok[pos] = p >> 1;
    wsl[pos] = tkw[p];
  }
}

// ---------------------------------------------------------------------------
// xb = (bf16) x   — 16 elems/thread, 2048 blocks (R14-verified)
__global__ void xcast(const float* __restrict__ x, __hip_bfloat16* __restrict__ xb) {
  const size_t base = ((size_t)blockIdx.x * 256 + threadIdx.x) * 16;
#pragma unroll
  for (int h = 0; h < 2; ++h) {
    f32x4 v0 = *(const f32x4*)(x + base + h * 8);
    f32x4 v1 = *(const f32x4*)(x + base + h * 8 + 4);
    union { __hip_bfloat16 b[8]; uint2 u[2]; } cv;
#pragma unroll
    for (int j = 0; j < 4; ++j) {
      cv.b[j]     = __float2bfloat16(v0[j]);
      cv.b[4 + j] = __float2bfloat16(v1[j]);
    }
    *(uint2*)(xb + base + h * 8)     = cv.u[0];
    *(uint2*)(xb + base + h * 8 + 4) = cv.u[1];
  }
}

// ---------------------------------------------------------------------------
// wt[e][f][h] = (bf16) w[e][h][f].  64x64 tiles, 256 threads (R13-verified).
__global__ void transpose_cast(const float* __restrict__ w1, const float* __restrict__ w2,
                               __hip_bfloat16* __restrict__ wt1, __hip_bfloat16* __restrict__ wt2) {
  __shared__ __hip_bfloat16 t[64][65];
  const int z = blockIdx.z;
  const float* W = (z < E_ ? w1 : w2) + ((size_t)(z & 7) << 20);
  __hip_bfloat16* WT = (z < E_ ? wt1 : wt2) + ((size_t)(z & 7) << 20);
  const int h0 = blockIdx.y * 64, f0 = blockIdx.x * 64;
  const int tid = threadIdx.x;
  const int tx = tid & 63, ty = tid >> 6;
#pragma unroll
  for (int i = 0; i < 16; ++i) {
    const int hl = i * 4 + ty;
    t[hl][tx] = __float2bfloat16(W[(size_t)(h0 + hl) * H_ + f0 + tx]);
  }
  __syncthreads();
  const int htx = tid & 15;
  const int fy  = tid >> 4;
#pragma unroll
  for (int j = 0; j < 4; ++j) {
    const int f = j * 16 + fy;
    union { __hip_bfloat16 h[4]; uint2 u; } v;
#pragma unroll
    for (int k = 0; k < 4; ++k) v.h[k] = t[htx * 4 + k][f];
    *reinterpret_cast<uint2*>(&WT[(size_t)(f0 + f) * H_ + h0 + htx * 4]) = v.u;
  }
}

// ---------------------------------------------------------------------------
// Grouped GEMM, single-buffer reg-staged, raw-barrier loop (R12-R16 verified):
//   { loadreg(kt+1) ; compute(kt) } -> lgkm0+bar -> dswrite(kt+1) -> lgkm0+bar
//   EPI=0: A = xb rows gathered via tok;  h1 = relu(AW^T+b)
//   EPI=1: A = h1 rows (linear);          out[tok[p]] += wsl[p]*(AW^T+b)
#define FENCE_BAR() do {                                   \
    asm volatile("s_waitcnt lgkmcnt(0)" ::: "memory");     \
    __builtin_amdgcn_s_barrier();                          \
    __builtin_amdgcn_sched_barrier(0);                     \
  } while (0)

template <int EPI>
__launch_bounds__(256, 4)   // enforces VGPR<=128 -> 4 blocks/CU -> capacity 1024
__global__ void moe_gemm(const __hip_bfloat16* __restrict__ Asrc,  // xb (EPI=0) / h1 (EPI=1)
                         const __hip_bfloat16* __restrict__ Wt,    // [E][H][H] (f-major)
                         const float* __restrict__ bias,           // [E][H]
                         __hip_bfloat16* __restrict__ h1out,
                         float* __restrict__ out,
                         const int* __restrict__ cnt,
                         const int* __restrict__ tok, const float* __restrict__ wsl) {
  // T1: bijective XCD swizzle (NWG % 8 == 0)
  const int wgid = (blockIdx.x & 7) * (NWG / 8) + (blockIdx.x >> 3);
  const int bt = wgid >> 3;
  const int nt = wgid & 7;

  // inline per-expert tile prefix from cnt[8] (R14-verified)
  int cn[E_];
#pragma unroll
  for (int i = 0; i < E_; ++i) cn[i] = cnt[i];
  int e = -1, mt = 0, count = 0, arow0 = 0;
  {
    int tacc = 0, sacc = 0;
#pragma unroll
    for (int i = 0; i < E_; ++i) {
      const int nti = (cn[i] + BM - 1) / BM;
      if (e < 0 && bt < tacc + nti) { e = i; mt = bt - tacc; count = cn[i]; arow0 = sacc + mt * BM; }
      tacc += nti; sacc += cn[i];
    }
  }
  if (e < 0) return;
  const size_t Arow0 = (size_t)arow0;

  const int tid = threadIdx.x;
  const int lane = tid & 63;
  const int wid = tid >> 6;
  const int wm = wid >> 1, wn = wid & 1;      // 2x2 waves; per-wave 80x64
  const int l15 = lane & 15, hi = lane >> 4, l7 = lane & 7;

  const __hip_bfloat16* Bexp = Wt + ((size_t)e << 20) + (size_t)(nt * BN) * H_;

  __shared__ __hip_bfloat16 smA[BM * BK];  // 20.0 KB
  __shared__ __hip_bfloat16 smB[BN * BK];  // 36.9 KB total -> 4 blocks/CU

  const int srow = tid >> 3;         // 0..31
  const int sun  = (tid & 7) * 8;    // linear global source offset (coalesced)
  const int swu  = (((tid & 7) ^ (srow & 7)) * 8);   // XOR-swizzled LDS unit (R4-verified)

  const __hip_bfloat16* aptr[5];
#pragma unroll
  for (int i = 0; i < 5; ++i) {
    if constexpr (EPI == 0) {
      int p = arow0 + i * 32 + srow;
      if (p > NSLOT - 1) p = NSLOT - 1;
      aptr[i] = Asrc + (size_t)tok[p] * H_ + sun;
    } else {
      aptr[i] = Asrc + (Arow0 + i * 32 + srow) * H_ + sun;   // h1 has +2048-row slack
    }
  }
  const __hip_bfloat16* bptr = Bexp + (size_t)srow * H_ + sun;

  short8_t ra[5], rb[4];

  auto loadreg = [&](int kt) {
#pragma unroll
    for (int i = 0; i < 5; ++i)
      ra[i] = *(const short8_t*)(aptr[i] + kt * BK);
#pragma unroll
    for (int i = 0; i < 4; ++i)
      rb[i] = *(const short8_t*)(bptr + (size_t)(i * 32) * H_ + kt * BK);
  };
  auto dswrite = [&]() {
#pragma unroll
    for (int i = 0; i < 5; ++i)
      *(short8_t*)&smA[(i * 32 + srow) * BK + swu] = ra[i];
#pragma unroll
    for (int i = 0; i < 4; ++i)
      *(short8_t*)&smB[(i * 32 + srow) * BK + swu] = rb[i];
  };

  f32x4 acc[5][4];
#pragma unroll
  for (int mi = 0; mi < 5; ++mi)
#pragma unroll
    for (int ni = 0; ni < 4; ++ni) acc[mi][ni] = f32x4{0.f, 0.f, 0.f, 0.f};

  // ds_read swizzle: logical unit (ks*4+hi) of row r at phys (ks*4+hi)^(r&7); r&7==l7
  const int pu[2] = { ((0 * 4 + hi) ^ l7) * 8, ((1 * 4 + hi) ^ l7) * 8 };

  auto compute = [&]() {
#pragma unroll
    for (int ks = 0; ks < 2; ++ks) {
      short8_t a[5], b[4];
#pragma unroll
      for (int mi = 0; mi < 5; ++mi)
        a[mi] = *(const short8_t*)&smA[(wm * 80 + mi * 16 + l15) * BK + pu[ks]];
#pragma unroll
      for (int ni = 0; ni < 4; ++ni)
        b[ni] = *(const short8_t*)&smB[(wn * 64 + ni * 16 + l15) * BK + pu[ks]];
#pragma unroll
      for (int mi = 0; mi < 5; ++mi)
#pragma unroll
        for (int ni = 0; ni < 4; ++ni)
          acc[mi][ni] = __builtin_amdgcn_mfma_f32_16x16x32_bf16(a[mi], b[ni], acc[mi][ni], 0, 0, 0);
    }
  };

  const int KT = H_ / BK;  // 16

  loadreg(0);
  dswrite();
  FENCE_BAR();

  for (int kt = 0; kt < KT; ++kt) {
    if (kt + 1 < KT) loadreg(kt + 1);  // in flight through compute + barrier
    compute();
    if (kt + 1 < KT) {
      FENCE_BAR();                      // all waves done reading tile kt
      dswrite();                        // counted per-reg vmcnt waits only
      FENCE_BAR();                      // writes visible
    }
  }

  // ---- epilogue: per-(mi,r) hoisted bound check (R13-verified) ----
  const int colb = nt * BN + wn * 64;
  float bv[4];
#pragma unroll
  for (int ni = 0; ni < 4; ++ni) bv[ni] = bias[e * H_ + colb + ni * 16 + l15];

  if constexpr (EPI == 0) {
#pragma unroll
    for (int mi = 0; mi < 5; ++mi)
#pragma unroll
      for (int r = 0; r < 4; ++r) {
        const int lr = wm * 80 + mi * 16 + hi * 4 + r;
        if (mt * BM + lr < count) {
          __hip_bfloat16* rp = h1out + (Arow0 + lr) * H_ + colb;
#pragma unroll
          for (int ni = 0; ni < 4; ++ni) {
            float v = acc[mi][ni][r] + bv[ni];
            rp[ni * 16 + l15] = __float2bfloat16(fmaxf(v, 0.f));
          }
        }
      }
  } else {
#pragma unroll
    for (int mi = 0; mi < 5; ++mi)
#pragma unroll
      for (int r = 0; r < 4; ++r) {
        const int lr = wm * 80 + mi * 16 + hi * 4 + r;
        if (mt * BM + lr < count) {
          const int p = arow0 + lr;
          float* rp = out + (size_t)tok[p] * H_ + colb;
          const float w = wsl[p];
#pragma unroll
          for (int ni = 0; ni < 4; ++ni)
            atomicAdd(rp + ni * 16 + l15, (acc[mi][ni][r] + bv[ni]) * w);
        }
      }
  }
}

// ---------------------------------------------------------------------------
extern "C" void kernel_launch(void* const* d_in, const int* in_sizes, int n_in,
                              void* d_out, int out_size, void* d_ws, size_t ws_size,
                              hipStream_t stream) {
  const float* x   = (const float*)d_in[0];
  const int*   idx = (const int*)d_in[1];
  const float* tkw = (const float*)d_in[2];
  const float* w1  = (const float*)d_in[3];
  const float* b1  = (const float*)d_in[4];
  const float* w2  = (const float*)d_in[5];
  const float* b2  = (const float*)d_in[6];
  float* out = (float*)d_out;

  uint8_t* ws = (uint8_t*)d_ws;
  int*   cnt  = (int*)(ws + CNT_OFF);
  int*   cur  = (int*)(ws + CUR_OFF);
  int*   tok  = (int*)(ws + TOK_OFF);
  float* wsl  = (float*)(ws + WSL_OFF);
  __hip_bfloat16* xb  = (__hip_bfloat16*)(ws + XB_OFF);
  __hip_bfloat16* h1  = (__hip_bfloat16*)(ws + H1_OFF);
  __hip_bfloat16* w1t = (__hip_bfloat16*)(ws + W1T_OFF);
  __hip_bfloat16* w2t = (__hip_bfloat16*)(ws + W2T_OFF);

  hipMemsetAsync(ws, 0, 1024, stream);
  hipMemsetAsync(d_out, 0, (size_t)out_size * sizeof(float), stream);

  xcast<<<NTOK * H_ / (256 * 16), 256, 0, stream>>>(x, xb);
  transpose_cast<<<dim3(H_ / 64, H_ / 64, 2 * E_), 256, 0, stream>>>(w1, w2, w1t, w2t);

  route_count<<<NSLOT / 256, 256, 0, stream>>>(idx, cnt);
  route_scatter<<<NSLOT / 256, 256, 0, stream>>>(idx, tkw, cnt, cur, tok, wsl);

  moe_gemm<0><<<NWG, 256, 0, stream>>>(xb, w1t, b1, h1, nullptr, cnt, tok, wsl);
  moe_gemm<1><<<NWG, 256, 0, stream>>>(h1, w2t, b2, nullptr, out, cnt, tok, wsl);
}

// Round 18
// 290.455 us; speedup vs baseline: 1.3059x; 1.0198x over previous
//
#include <hip/hip_runtime.h>
#include <hip/hip_bf16.h>
#include <stdint.h>

// Problem constants (B=4, S=2048, H=1024, E=8, K=2)
#define E_    8
#define H_    1024
#define NTOK  8192           // B*S
#define KSEL  2
#define NSLOT (NTOK * KSEL)  // 16384

typedef __attribute__((ext_vector_type(8))) short   short8_t;  // 8 bf16 in 4 VGPRs
typedef __attribute__((ext_vector_type(4))) float   f32x4;

// GEMM tiling (R17-verified best): 160x128, BK=64, 4 waves, reg-staged bf16,
// XOR-swizzled LDS (36.9KB -> 4 blocks/CU, conflicts=0), raw lgkm-only
// barriers, NWG=880 <= capacity 1024.
#define BM 160
#define BN 128
#define BK 64
#define MAXMT 110
#define NT    (H_ / BN)      // 8 N-tiles
#define NWG   (MAXMT * NT)   // 880, div by 8

// ---- workspace layout (bytes) ----
#define CNT_OFF   0
#define CUR_OFF   64
#define TOK_OFF   1024                     // NSLOT ints
#define WSL_OFF   (TOK_OFF + NSLOT * 4)    // NSLOT floats
#define XB_OFF    (1 << 18)                              // bf16 x (16.8 MB)
#define H1_OFF    (XB_OFF + (size_t)NTOK * H_ * 2)
#define W1T_OFF   (H1_OFF + (size_t)(NSLOT + 2048) * H_ * 2)
#define W2T_OFF   (W1T_OFF + (size_t)E_ * H_ * H_ * 2)

// ---------------------------------------------------------------------------
__global__ void route_count(const int* __restrict__ idx, int* __restrict__ cnt) {
  int p = blockIdx.x * 256 + threadIdx.x;
  if (p < NSLOT) atomicAdd(&cnt[idx[p]], 1);
}

// ---------------------------------------------------------------------------
// Fused: blocks [0,64) = route_scatter; blocks [64,2112) = xcast + out-zero.
// (scatter needs final cnt — route_count is the previous node.)
__global__ void fused_scatter_xcast(const int* __restrict__ idx, const float* __restrict__ tkw,
                                    const int* __restrict__ cnt, int* __restrict__ cur,
                                    int* __restrict__ tok, float* __restrict__ wsl,
                                    const float* __restrict__ x, __hip_bfloat16* __restrict__ xb,
                                    float* __restrict__ out) {
  const int tid = threadIdx.x;
  if (blockIdx.x < 64) {
    // scatter (R14-verified inline-prefix form)
    int p = blockIdx.x * 256 + tid;
    const int e = idx[p];
    int off = 0;
#pragma unroll
    for (int i = 0; i < E_; ++i) off += (i < e) ? cnt[i] : 0;
    const int pos = off + atomicAdd(&cur[e], 1);
    tok[pos] = p >> 1;
    wsl[pos] = tkw[p];
  } else {
    const size_t base = ((size_t)(blockIdx.x - 64) * 256 + tid) * 16;
    // out zero (16 floats)
    f32x4 z = f32x4{0.f, 0.f, 0.f, 0.f};
#pragma unroll
    for (int j = 0; j < 4; ++j) *(f32x4*)(out + base + j * 4) = z;
    // xcast (16 elems, R14-verified)
#pragma unroll
    for (int h = 0; h < 2; ++h) {
      f32x4 v0 = *(const f32x4*)(x + base + h * 8);
      f32x4 v1 = *(const f32x4*)(x + base + h * 8 + 4);
      union { __hip_bfloat16 b[8]; uint2 u[2]; } cv;
#pragma unroll
      for (int j = 0; j < 4; ++j) {
        cv.b[j]     = __float2bfloat16(v0[j]);
        cv.b[4 + j] = __float2bfloat16(v1[j]);
      }
      *(uint2*)(xb + base + h * 8)     = cv.u[0];
      *(uint2*)(xb + base + h * 8 + 4) = cv.u[1];
    }
  }
}

// ---------------------------------------------------------------------------
// wt[e][f][h] = (bf16) w[e][h][f].  64x64 tiles, 256 threads (R13-verified).
// Block (0,0,0) additionally zeroes cnt/cur (route_count runs in a LATER node).
__global__ void transpose_cast(const float* __restrict__ w1, const float* __restrict__ w2,
                               __hip_bfloat16* __restrict__ wt1, __hip_bfloat16* __restrict__ wt2,
                               int* __restrict__ counters) {
  if (blockIdx.x == 0 && blockIdx.y == 0 && blockIdx.z == 0 && threadIdx.x < 64)
    counters[threadIdx.x] = 0;   // bytes 0..255: cnt + cur
  __shared__ __hip_bfloat16 t[64][65];
  const int z = blockIdx.z;
  const float* W = (z < E_ ? w1 : w2) + ((size_t)(z & 7) << 20);
  __hip_bfloat16* WT = (z < E_ ? wt1 : wt2) + ((size_t)(z & 7) << 20);
  const int h0 = blockIdx.y * 64, f0 = blockIdx.x * 64;
  const int tid = threadIdx.x;
  const int tx = tid & 63, ty = tid >> 6;
#pragma unroll
  for (int i = 0; i < 16; ++i) {
    const int hl = i * 4 + ty;
    t[hl][tx] = __float2bfloat16(W[(size_t)(h0 + hl) * H_ + f0 + tx]);
  }
  __syncthreads();
  const int htx = tid & 15;
  const int fy  = tid >> 4;
#pragma unroll
  for (int j = 0; j < 4; ++j) {
    const int f = j * 16 + fy;
    union { __hip_bfloat16 h[4]; uint2 u; } v;
#pragma unroll
    for (int k = 0; k < 4; ++k) v.h[k] = t[htx * 4 + k][f];
    *reinterpret_cast<uint2*>(&WT[(size_t)(f0 + f) * H_ + h0 + htx * 4]) = v.u;
  }
}

// ---------------------------------------------------------------------------
// Grouped GEMM — byte-identical to R17 (best measured: 84us, conflicts 0).
#define FENCE_BAR() do {                                   \
    asm volatile("s_waitcnt lgkmcnt(0)" ::: "memory");     \
    __builtin_amdgcn_s_barrier();                          \
    __builtin_amdgcn_sched_barrier(0);                     \
  } while (0)

template <int EPI>
__launch_bounds__(256, 4)
__global__ void moe_gemm(const __hip_bfloat16* __restrict__ Asrc,  // xb (EPI=0) / h1 (EPI=1)
                         const __hip_bfloat16* __restrict__ Wt,    // [E][H][H] (f-major)
                         const float* __restrict__ bias,           // [E][H]
                         __hip_bfloat16* __restrict__ h1out,
                         float* __restrict__ out,
                         const int* __restrict__ cnt,
                         const int* __restrict__ tok, const float* __restrict__ wsl) {
  const int wgid = (blockIdx.x & 7) * (NWG / 8) + (blockIdx.x >> 3);
  const int bt = wgid >> 3;
  const int nt = wgid & 7;

  int cn[E_];
#pragma unroll
  for (int i = 0; i < E_; ++i) cn[i] = cnt[i];
  int e = -1, mt = 0, count = 0, arow0 = 0;
  {
    int tacc = 0, sacc = 0;
#pragma unroll
    for (int i = 0; i < E_; ++i) {
      const int nti = (cn[i] + BM - 1) / BM;
      if (e < 0 && bt < tacc + nti) { e = i; mt = bt - tacc; count = cn[i]; arow0 = sacc + mt * BM; }
      tacc += nti; sacc += cn[i];
    }
  }
  if (e < 0) return;
  const size_t Arow0 = (size_t)arow0;

  const int tid = threadIdx.x;
  const int lane = tid & 63;
  const int wid = tid >> 6;
  const int wm = wid >> 1, wn = wid & 1;      // 2x2 waves; per-wave 80x64
  const int l15 = lane & 15, hi = lane >> 4, l7 = lane & 7;

  const __hip_bfloat16* Bexp = Wt + ((size_t)e << 20) + (size_t)(nt * BN) * H_;

  __shared__ __hip_bfloat16 smA[BM * BK];  // 20.0 KB
  __shared__ __hip_bfloat16 smB[BN * BK];  // 36.9 KB total -> 4 blocks/CU

  const int srow = tid >> 3;
  const int sun  = (tid & 7) * 8;
  const int swu  = (((tid & 7) ^ (srow & 7)) * 8);

  const __hip_bfloat16* aptr[5];
#pragma unroll
  for (int i = 0; i < 5; ++i) {
    if constexpr (EPI == 0) {
      int p = arow0 + i * 32 + srow;
      if (p > NSLOT - 1) p = NSLOT - 1;
      aptr[i] = Asrc + (size_t)tok[p] * H_ + sun;
    } else {
      aptr[i] = Asrc + (Arow0 + i * 32 + srow) * H_ + sun;
    }
  }
  const __hip_bfloat16* bptr = Bexp + (size_t)srow * H_ + sun;

  short8_t ra[5], rb[4];

  auto loadreg = [&](int kt) {
#pragma unroll
    for (int i = 0; i < 5; ++i)
      ra[i] = *(const short8_t*)(aptr[i] + kt * BK);
#pragma unroll
    for (int i = 0; i < 4; ++i)
      rb[i] = *(const short8_t*)(bptr + (size_t)(i * 32) * H_ + kt * BK);
  };
  auto dswrite = [&]() {
#pragma unroll
    for (int i = 0; i < 5; ++i)
      *(short8_t*)&smA[(i * 32 + srow) * BK + swu] = ra[i];
#pragma unroll
    for (int i = 0; i < 4; ++i)
      *(short8_t*)&smB[(i * 32 + srow) * BK + swu] = rb[i];
  };

  f32x4 acc[5][4];
#pragma unroll
  for (int mi = 0; mi < 5; ++mi)
#pragma unroll
    for (int ni = 0; ni < 4; ++ni) acc[mi][ni] = f32x4{0.f, 0.f, 0.f, 0.f};

  const int pu[2] = { ((0 * 4 + hi) ^ l7) * 8, ((1 * 4 + hi) ^ l7) * 8 };

  auto compute = [&]() {
#pragma unroll
    for (int ks = 0; ks < 2; ++ks) {
      short8_t a[5], b[4];
#pragma unroll
      for (int mi = 0; mi < 5; ++mi)
        a[mi] = *(const short8_t*)&smA[(wm * 80 + mi * 16 + l15) * BK + pu[ks]];
#pragma unroll
      for (int ni = 0; ni < 4; ++ni)
        b[ni] = *(const short8_t*)&smB[(wn * 64 + ni * 16 + l15) * BK + pu[ks]];
#pragma unroll
      for (int mi = 0; mi < 5; ++mi)
#pragma unroll
        for (int ni = 0; ni < 4; ++ni)
          acc[mi][ni] = __builtin_amdgcn_mfma_f32_16x16x32_bf16(a[mi], b[ni], acc[mi][ni], 0, 0, 0);
    }
  };

  const int KT = H_ / BK;  // 16

  loadreg(0);
  dswrite();
  FENCE_BAR();

  for (int kt = 0; kt < KT; ++kt) {
    if (kt + 1 < KT) loadreg(kt + 1);
    compute();
    if (kt + 1 < KT) {
      FENCE_BAR();
      dswrite();
      FENCE_BAR();
    }
  }

  const int colb = nt * BN + wn * 64;
  float bv[4];
#pragma unroll
  for (int ni = 0; ni < 4; ++ni) bv[ni] = bias[e * H_ + colb + ni * 16 + l15];

  if constexpr (EPI == 0) {
#pragma unroll
    for (int mi = 0; mi < 5; ++mi)
#pragma unroll
      for (int r = 0; r < 4; ++r) {
        const int lr = wm * 80 + mi * 16 + hi * 4 + r;
        if (mt * BM + lr < count) {
          __hip_bfloat16* rp = h1out + (Arow0 + lr) * H_ + colb;
#pragma unroll
          for (int ni = 0; ni < 4; ++ni) {
            float v = acc[mi][ni][r] + bv[ni];
            rp[ni * 16 + l15] = __float2bfloat16(fmaxf(v, 0.f));
          }
        }
      }
  } else {
#pragma unroll
    for (int mi = 0; mi < 5; ++mi)
#pragma unroll
      for (int r = 0; r < 4; ++r) {
        const int lr = wm * 80 + mi * 16 + hi * 4 + r;
        if (mt * BM + lr < count) {
          const int p = arow0 + lr;
          float* rp = out + (size_t)tok[p] * H_ + colb;
          const float w = wsl[p];
#pragma unroll
          for (int ni = 0; ni < 4; ++ni)
            atomicAdd(rp + ni * 16 + l15, (acc[mi][ni][r] + bv[ni]) * w);
        }
      }
  }
}

// ---------------------------------------------------------------------------
extern "C" void kernel_launch(void* const* d_in, const int* in_sizes, int n_in,
                              void* d_out, int out_size, void* d_ws, size_t ws_size,
                              hipStream_t stream) {
  const float* x   = (const float*)d_in[0];
  const int*   idx = (const int*)d_in[1];
  const float* tkw = (const float*)d_in[2];
  const float* w1  = (const float*)d_in[3];
  const float* b1  = (const float*)d_in[4];
  const float* w2  = (const float*)d_in[5];
  const float* b2  = (const float*)d_in[6];
  float* out = (float*)d_out;

  uint8_t* ws = (uint8_t*)d_ws;
  int*   cnt  = (int*)(ws + CNT_OFF);
  int*   cur  = (int*)(ws + CUR_OFF);
  int*   tok  = (int*)(ws + TOK_OFF);
  float* wsl  = (float*)(ws + WSL_OFF);
  __hip_bfloat16* xb  = (__hip_bfloat16*)(ws + XB_OFF);
  __hip_bfloat16* h1  = (__hip_bfloat16*)(ws + H1_OFF);
  __hip_bfloat16* w1t = (__hip_bfloat16*)(ws + W1T_OFF);
  __hip_bfloat16* w2t = (__hip_bfloat16*)(ws + W2T_OFF);

  // node 1: weight transpose+cast; block(0,0,0) zeroes cnt/cur
  transpose_cast<<<dim3(H_ / 64, H_ / 64, 2 * E_), 256, 0, stream>>>(w1, w2, w1t, w2t, (int*)ws);
  // node 2: per-expert counts
  route_count<<<NSLOT / 256, 256, 0, stream>>>(idx, cnt);
  // node 3: scatter + xcast + out-zero (fused)
  fused_scatter_xcast<<<64 + NTOK * H_ / (256 * 16), 256, 0, stream>>>(
      idx, tkw, cnt, cur, tok, wsl, x, xb, out);
  // nodes 4-5: grouped GEMMs (R17-verified)
  moe_gemm<0><<<NWG, 256, 0, stream>>>(xb, w1t, b1, h1, nullptr, cnt, tok, wsl);
  moe_gemm<1><<<NWG, 256, 0, stream>>>(h1, w2t, b2, nullptr, out, cnt, tok, wsl);
}

// Round 19
// 186.036 us; speedup vs baseline: 2.0388x; 1.5613x over previous
//
#include <hip/hip_runtime.h>
#include <hip/hip_bf16.h>
#include <stdint.h>

// Problem constants (B=4, S=2048, H=1024, E=8, K=2)
#define E_    8
#define H_    1024
#define NTOK  8192           // B*S
#define KSEL  2
#define NSLOT (NTOK * KSEL)  // 16384

typedef __attribute__((ext_vector_type(8))) short   short8_t;  // 8 bf16 in 4 VGPRs
typedef __attribute__((ext_vector_type(4))) float   f32x4;

// GEMM tiling (R17/R18-verified best): 160x128, BK=64, 4 waves, reg-staged
// bf16, XOR-swizzled LDS (36.9KB -> 4 blocks/CU, conflicts=0), raw lgkm-only
// barriers, NWG=880 <= capacity 1024.
#define BM 160
#define BN 128
#define BK 64
#define MAXMT 110
#define NT    (H_ / BN)      // 8 N-tiles
#define NWG   (MAXMT * NT)   // 880, div by 8

// ---- workspace layout (bytes) ----
#define CNT_OFF   0
#define TOK_OFF   1024                     // NSLOT ints
#define WSL_OFF   (TOK_OFF + NSLOT * 4)    // NSLOT floats
#define XB_OFF    (1 << 18)                              // bf16 x (16.8 MB)
#define H1_OFF    (XB_OFF + (size_t)NTOK * H_ * 2)
#define W1T_OFF   (H1_OFF + (size_t)(NSLOT + 2048) * H_ * 2)
#define W2T_OFF   (W1T_OFF + (size_t)E_ * H_ * H_ * 2)

// ---------------------------------------------------------------------------
// Single-block deterministic router: NO global atomics (R18 post-mortem:
// 16384 atomicAdds on 8 counters serialized ~85us). 1024 threads x 16 slots.
// Phase 1: per-thread histogram (static-indexed, rule 20).
// Scan:    Hillis-Steele over 1024 threads x 8 experts in LDS.
// Phase 2: re-walk slots, assign positions from register cursors.
#define RT_T 1024
#define RT_S (NSLOT / RT_T)   // 16 slots per thread

__global__ __launch_bounds__(RT_T) void route_all(
    const int* __restrict__ idx, const float* __restrict__ tkw,
    int* __restrict__ cnt, int* __restrict__ tok, float* __restrict__ wsl) {
  __shared__ int hist[E_ * RT_T];   // 32 KB: hist[j*RT_T + t]
  const int t = threadIdx.x;
  const int p0 = t * RT_S;

  // phase 1: cache idx, count per-expert (static indexing only)
  int myi[RT_S];
#pragma unroll
  for (int i = 0; i < RT_S; i += 4)
    *(int4*)&myi[i] = *(const int4*)&idx[p0 + i];
  int lc[E_];
#pragma unroll
  for (int j = 0; j < E_; ++j) lc[j] = 0;
#pragma unroll
  for (int i = 0; i < RT_S; ++i)
#pragma unroll
    for (int j = 0; j < E_; ++j) lc[j] += (myi[i] == j) ? 1 : 0;

#pragma unroll
  for (int j = 0; j < E_; ++j) hist[j * RT_T + t] = lc[j];
  __syncthreads();

  // inclusive scan across threads (per expert)
  for (int s = 1; s < RT_T; s <<= 1) {
    int v[E_];
#pragma unroll
    for (int j = 0; j < E_; ++j) v[j] = (t >= s) ? hist[j * RT_T + (t - s)] : 0;
    __syncthreads();
#pragma unroll
    for (int j = 0; j < E_; ++j) hist[j * RT_T + t] += v[j];
    __syncthreads();
  }

  // totals + expert bases (same in all threads)
  int tot[E_];
#pragma unroll
  for (int j = 0; j < E_; ++j) tot[j] = hist[j * RT_T + (RT_T - 1)];
  int base[E_];
  {
    int s = 0;
#pragma unroll
    for (int j = 0; j < E_; ++j) { base[j] = s; s += tot[j]; }
  }
  if (t < E_) cnt[t] = tot[t];

  // per-thread running cursors: exclusive prefix = inclusive - own
  int cur[E_];
#pragma unroll
  for (int j = 0; j < E_; ++j) cur[j] = base[j] + hist[j * RT_T + t] - lc[j];

  // phase 2: assign (deterministic slot order)
  float myw[RT_S];
#pragma unroll
  for (int i = 0; i < RT_S; i += 4)
    *(float4*)&myw[i] = *(const float4*)&tkw[p0 + i];
#pragma unroll
  for (int i = 0; i < RT_S; ++i) {
    const int ev = myi[i];
    int pos = 0;
#pragma unroll
    for (int j = 0; j < E_; ++j)
      if (ev == j) { pos = cur[j]; cur[j] = pos + 1; }
    tok[pos] = (p0 + i) >> 1;
    wsl[pos] = myw[i];
  }
}

// ---------------------------------------------------------------------------
// xb = (bf16) x  +  out zero.  16 elems/thread, 2048 blocks.
__global__ void xcast_zero(const float* __restrict__ x, __hip_bfloat16* __restrict__ xb,
                           float* __restrict__ out) {
  const size_t base = ((size_t)blockIdx.x * 256 + threadIdx.x) * 16;
  f32x4 z = f32x4{0.f, 0.f, 0.f, 0.f};
#pragma unroll
  for (int j = 0; j < 4; ++j) *(f32x4*)(out + base + j * 4) = z;
#pragma unroll
  for (int h = 0; h < 2; ++h) {
    f32x4 v0 = *(const f32x4*)(x + base + h * 8);
    f32x4 v1 = *(const f32x4*)(x + base + h * 8 + 4);
    union { __hip_bfloat16 b[8]; uint2 u[2]; } cv;
#pragma unroll
    for (int j = 0; j < 4; ++j) {
      cv.b[j]     = __float2bfloat16(v0[j]);
      cv.b[4 + j] = __float2bfloat16(v1[j]);
    }
    *(uint2*)(xb + base + h * 8)     = cv.u[0];
    *(uint2*)(xb + base + h * 8 + 4) = cv.u[1];
  }
}

// ---------------------------------------------------------------------------
// wt[e][f][h] = (bf16) w[e][h][f].  64x64 tiles, 256 threads (R13-verified).
__global__ void transpose_cast(const float* __restrict__ w1, const float* __restrict__ w2,
                               __hip_bfloat16* __restrict__ wt1, __hip_bfloat16* __restrict__ wt2) {
  __shared__ __hip_bfloat16 t[64][65];
  const int z = blockIdx.z;
  const float* W = (z < E_ ? w1 : w2) + ((size_t)(z & 7) << 20);
  __hip_bfloat16* WT = (z < E_ ? wt1 : wt2) + ((size_t)(z & 7) << 20);
  const int h0 = blockIdx.y * 64, f0 = blockIdx.x * 64;
  const int tid = threadIdx.x;
  const int tx = tid & 63, ty = tid >> 6;
#pragma unroll
  for (int i = 0; i < 16; ++i) {
    const int hl = i * 4 + ty;
    t[hl][tx] = __float2bfloat16(W[(size_t)(h0 + hl) * H_ + f0 + tx]);
  }
  __syncthreads();
  const int htx = tid & 15;
  const int fy  = tid >> 4;
#pragma unroll
  for (int j = 0; j < 4; ++j) {
    const int f = j * 16 + fy;
    union { __hip_bfloat16 h[4]; uint2 u; } v;
#pragma unroll
    for (int k = 0; k < 4; ++k) v.h[k] = t[htx * 4 + k][f];
    *reinterpret_cast<uint2*>(&WT[(size_t)(f0 + f) * H_ + h0 + htx * 4]) = v.u;
  }
}

// ---------------------------------------------------------------------------
// Grouped GEMM — byte-identical to R17/R18 (best measured: 84us, conflicts 0).
#define FENCE_BAR() do {                                   \
    asm volatile("s_waitcnt lgkmcnt(0)" ::: "memory");     \
    __builtin_amdgcn_s_barrier();                          \
    __builtin_amdgcn_sched_barrier(0);                     \
  } while (0)

template <int EPI>
__launch_bounds__(256, 4)
__global__ void moe_gemm(const __hip_bfloat16* __restrict__ Asrc,  // xb (EPI=0) / h1 (EPI=1)
                         const __hip_bfloat16* __restrict__ Wt,    // [E][H][H] (f-major)
                         const float* __restrict__ bias,           // [E][H]
                         __hip_bfloat16* __restrict__ h1out,
                         float* __restrict__ out,
                         const int* __restrict__ cnt,
                         const int* __restrict__ tok, const float* __restrict__ wsl) {
  const int wgid = (blockIdx.x & 7) * (NWG / 8) + (blockIdx.x >> 3);
  const int bt = wgid >> 3;
  const int nt = wgid & 7;

  int cn[E_];
#pragma unroll
  for (int i = 0; i < E_; ++i) cn[i] = cnt[i];
  int e = -1, mt = 0, count = 0, arow0 = 0;
  {
    int tacc = 0, sacc = 0;
#pragma unroll
    for (int i = 0; i < E_; ++i) {
      const int nti = (cn[i] + BM - 1) / BM;
      if (e < 0 && bt < tacc + nti) { e = i; mt = bt - tacc; count = cn[i]; arow0 = sacc + mt * BM; }
      tacc += nti; sacc += cn[i];
    }
  }
  if (e < 0) return;
  const size_t Arow0 = (size_t)arow0;

  const int tid = threadIdx.x;
  const int lane = tid & 63;
  const int wid = tid >> 6;
  const int wm = wid >> 1, wn = wid & 1;      // 2x2 waves; per-wave 80x64
  const int l15 = lane & 15, hi = lane >> 4, l7 = lane & 7;

  const __hip_bfloat16* Bexp = Wt + ((size_t)e << 20) + (size_t)(nt * BN) * H_;

  __shared__ __hip_bfloat16 smA[BM * BK];  // 20.0 KB
  __shared__ __hip_bfloat16 smB[BN * BK];  // 36.9 KB total -> 4 blocks/CU

  const int srow = tid >> 3;
  const int sun  = (tid & 7) * 8;
  const int swu  = (((tid & 7) ^ (srow & 7)) * 8);

  const __hip_bfloat16* aptr[5];
#pragma unroll
  for (int i = 0; i < 5; ++i) {
    if constexpr (EPI == 0) {
      int p = arow0 + i * 32 + srow;
      if (p > NSLOT - 1) p = NSLOT - 1;
      aptr[i] = Asrc + (size_t)tok[p] * H_ + sun;
    } else {
      aptr[i] = Asrc + (Arow0 + i * 32 + srow) * H_ + sun;
    }
  }
  const __hip_bfloat16* bptr = Bexp + (size_t)srow * H_ + sun;

  short8_t ra[5], rb[4];

  auto loadreg = [&](int kt) {
#pragma unroll
    for (int i = 0; i < 5; ++i)
      ra[i] = *(const short8_t*)(aptr[i] + kt * BK);
#pragma unroll
    for (int i = 0; i < 4; ++i)
      rb[i] = *(const short8_t*)(bptr + (size_t)(i * 32) * H_ + kt * BK);
  };
  auto dswrite = [&]() {
#pragma unroll
    for (int i = 0; i < 5; ++i)
      *(short8_t*)&smA[(i * 32 + srow) * BK + swu] = ra[i];
#pragma unroll
    for (int i = 0; i < 4; ++i)
      *(short8_t*)&smB[(i * 32 + srow) * BK + swu] = rb[i];
  };

  f32x4 acc[5][4];
#pragma unroll
  for (int mi = 0; mi < 5; ++mi)
#pragma unroll
    for (int ni = 0; ni < 4; ++ni) acc[mi][ni] = f32x4{0.f, 0.f, 0.f, 0.f};

  const int pu[2] = { ((0 * 4 + hi) ^ l7) * 8, ((1 * 4 + hi) ^ l7) * 8 };

  auto compute = [&]() {
#pragma unroll
    for (int ks = 0; ks < 2; ++ks) {
      short8_t a[5], b[4];
#pragma unroll
      for (int mi = 0; mi < 5; ++mi)
        a[mi] = *(const short8_t*)&smA[(wm * 80 + mi * 16 + l15) * BK + pu[ks]];
#pragma unroll
      for (int ni = 0; ni < 4; ++ni)
        b[ni] = *(const short8_t*)&smB[(wn * 64 + ni * 16 + l15) * BK + pu[ks]];
#pragma unroll
      for (int mi = 0; mi < 5; ++mi)
#pragma unroll
        for (int ni = 0; ni < 4; ++ni)
          acc[mi][ni] = __builtin_amdgcn_mfma_f32_16x16x32_bf16(a[mi], b[ni], acc[mi][ni], 0, 0, 0);
    }
  };

  const int KT = H_ / BK;  // 16

  loadreg(0);
  dswrite();
  FENCE_BAR();

  for (int kt = 0; kt < KT; ++kt) {
    if (kt + 1 < KT) loadreg(kt + 1);
    compute();
    if (kt + 1 < KT) {
      FENCE_BAR();
      dswrite();
      FENCE_BAR();
    }
  }

  const int colb = nt * BN + wn * 64;
  float bv[4];
#pragma unroll
  for (int ni = 0; ni < 4; ++ni) bv[ni] = bias[e * H_ + colb + ni * 16 + l15];

  if constexpr (EPI == 0) {
#pragma unroll
    for (int mi = 0; mi < 5; ++mi)
#pragma unroll
      for (int r = 0; r < 4; ++r) {
        const int lr = wm * 80 + mi * 16 + hi * 4 + r;
        if (mt * BM + lr < count) {
          __hip_bfloat16* rp = h1out + (Arow0 + lr) * H_ + colb;
#pragma unroll
          for (int ni = 0; ni < 4; ++ni) {
            float v = acc[mi][ni][r] + bv[ni];
            rp[ni * 16 + l15] = __float2bfloat16(fmaxf(v, 0.f));
          }
        }
      }
  } else {
#pragma unroll
    for (int mi = 0; mi < 5; ++mi)
#pragma unroll
      for (int r = 0; r < 4; ++r) {
        const int lr = wm * 80 + mi * 16 + hi * 4 + r;
        if (mt * BM + lr < count) {
          const int p = arow0 + lr;
          float* rp = out + (size_t)tok[p] * H_ + colb;
          const float w = wsl[p];
#pragma unroll
          for (int ni = 0; ni < 4; ++ni)
            atomicAdd(rp + ni * 16 + l15, (acc[mi][ni][r] + bv[ni]) * w);
        }
      }
  }
}

// ---------------------------------------------------------------------------
extern "C" void kernel_launch(void* const* d_in, const int* in_sizes, int n_in,
                              void* d_out, int out_size, void* d_ws, size_t ws_size,
                              hipStream_t stream) {
  const float* x   = (const float*)d_in[0];
  const int*   idx = (const int*)d_in[1];
  const float* tkw = (const float*)d_in[2];
  const float* w1  = (const float*)d_in[3];
  const float* b1  = (const float*)d_in[4];
  const float* w2  = (const float*)d_in[5];
  const float* b2  = (const float*)d_in[6];
  float* out = (float*)d_out;

  uint8_t* ws = (uint8_t*)d_ws;
  int*   cnt  = (int*)(ws + CNT_OFF);
  int*   tok  = (int*)(ws + TOK_OFF);
  float* wsl  = (float*)(ws + WSL_OFF);
  __hip_bfloat16* xb  = (__hip_bfloat16*)(ws + XB_OFF);
  __hip_bfloat16* h1  = (__hip_bfloat16*)(ws + H1_OFF);
  __hip_bfloat16* w1t = (__hip_bfloat16*)(ws + W1T_OFF);
  __hip_bfloat16* w2t = (__hip_bfloat16*)(ws + W2T_OFF);

  // node 1: weight transpose+cast
  transpose_cast<<<dim3(H_ / 64, H_ / 64, 2 * E_), 256, 0, stream>>>(w1, w2, w1t, w2t);
  // node 2: deterministic atomic-free routing (counts + scatter)
  route_all<<<1, RT_T, 0, stream>>>(idx, tkw, cnt, tok, wsl);
  // node 3: x cast + out zero
  xcast_zero<<<NTOK * H_ / (256 * 16), 256, 0, stream>>>(x, xb, out);
  // nodes 4-5: grouped GEMMs (R17-verified)
  moe_gemm<0><<<NWG, 256, 0, stream>>>(xb, w1t, b1, h1, nullptr, cnt, tok, wsl);
  moe_gemm<1><<<NWG, 256, 0, stream>>>(h1, w2t, b2, nullptr, out, cnt, tok, wsl);
}